// Round 1
// baseline (127.905 us; speedup 1.0000x reference)
//
#include <hip/hip_runtime.h>
#include <hip/hip_bf16.h>

// AdvancedLoss3D: vertex MSE + smoothness + symmetry + chamfer(B=4, N=8192)
// R16: fold both chamfer directions into ONE pass over unique pairs.
//  - Old: 2 passes (dir bit), 4 VALU/pair-visit = 8 VALU per unique pair.
//  - New: single pass computes full d2 (fma chain seeded with y2+r2) and
//    updates row-min (regs, min3) AND col-min (per-thread tree + 4-level
//    shfl_xor to 16-lane groups -> LDS, folded at block end) = ~6 VALU/pair.
//  - __launch_bounds__(256,4): cap VGPR at 128 (old kernel allocated 224
//    -> 2 waves/SIMD, OccupancyPercent 28.7%; the 1.76x gap vs the VALU
//    issue floor). 1024 blocks = 4/CU -> 4 waves/SIMD.
//  - Explicit 2-col LDS prefetch (yt padded) hides ds_read latency.
//
// ws float layout:
//  [0 .. 384)    aux partials: block b -> [3b]=vertex [3b+1]=smooth [3b+2]=sym
//  [384 .. 640)  reduce partials: block k -> sum of min-d for its 256 rows
//                (blocks 0..127 = pred-side rows, 128..255 = targ-side cols)
//  [1024 ..)     chamfer partial mins:
//                rows: slice s in [0,32): prow[s*32768 + b*8192 + row]
//                cols: at +32*32768, slice s in [0,8): pcol[s*32768 + b*8192 + col]

#define B_ 4
#define N_ 8192
#define MID_ (N_ / 2)
#define PMIN_OFF 1024
#define NROWSL 32                      // row-partial slices (32 col-chunks of 256)
#define NCOLSL 8                       // col-partial slices (8 row-chunks of 1024)
#define COL_OFF (NROWSL * (B_ * N_))   // col partials start (floats, within pm)

// Template-named symbol (same mangling as the round-0 stub). Never launched.
__global__ void AdvancedLoss3D_1881195675843_kernel() {}

__global__ __launch_bounds__(256) void aux_losses(const float* __restrict__ pred,
                                                  const float* __restrict__ targ,
                                                  float* __restrict__ ws) {
    int idx = blockIdx.x * 256 + threadIdx.x;  // 0 .. B_*N_-1 (grid = 128 blocks)
    int b = idx >> 13;
    int i = idx & (N_ - 1);
    const float* p = pred + (size_t)idx * 3;
    const float* t = targ + (size_t)idx * 3;
    float px = p[0], py = p[1], pz = p[2];
    float tx = t[0], ty = t[1], tz = t[2];
    float dx = px - tx, dy = py - ty, dz = pz - tz;
    float dv = dx * dx + dy * dy + dz * dz;     // vertex MSE numerator

    float sm = 0.f;                             // smoothness: ||p[i+1]-p[i]||
    if (i < N_ - 1) {
        float ex = p[3] - px, ey = p[4] - py, ez = p[5] - pz;
        sm = sqrtf(ex * ex + ey * ey + ez * ez);
    }

    float sy = 0.f;                             // symmetry: partner N-1-i, x negated
    if (i < MID_) {
        const float* r = pred + ((size_t)(b * N_ + (N_ - 1 - i))) * 3;
        float ax = px + r[0];                   // left.x - (-right.x)
        float ay = py - r[1];
        float az = pz - r[2];
        sy = ax * ax + ay * ay + az * az;
    }

    for (int off = 32; off; off >>= 1) {
        dv += __shfl_down(dv, off, 64);
        sm += __shfl_down(sm, off, 64);
        sy += __shfl_down(sy, off, 64);
    }
    __shared__ float red[3][4];
    int lane = threadIdx.x & 63, w = threadIdx.x >> 6;
    if (lane == 0) { red[0][w] = dv; red[1][w] = sm; red[2][w] = sy; }
    __syncthreads();
    if (threadIdx.x == 0) {
        ws[3 * blockIdx.x + 0] = red[0][0] + red[0][1] + red[0][2] + red[0][3];
        ws[3 * blockIdx.x + 1] = red[1][0] + red[1][1] + red[1][2] + red[1][3];
        ws[3 * blockIdx.x + 2] = red[2][0] + red[2][1] + red[2][2] + red[2][3];
    }
}

// 1024 blocks: bid = b(2) | nch(3) | mch(5)
// block tile: 1024 pred rows (4/thread, regs) x 256 targ cols (LDS, prescaled).
// Single pass updates BOTH row-min (pred side) and col-min (targ side).
__global__ __launch_bounds__(256, 4) void chamfer_pairs(const float* __restrict__ pred,
                                                        const float* __restrict__ targ,
                                                        float* __restrict__ pm) {
    int bid = blockIdx.x;
    int mch = bid & 31;          // col chunk: 256 targ cols
    int nch = (bid >> 5) & 7;    // row chunk: 1024 pred rows
    int b   = bid >> 8;

    __shared__ float4 yt[260];           // [256 cols + 4 pad] (-2x,-2y,-2z,|y|^2)
    __shared__ float clds[4][4][256];    // [wave][16-lane group][col] partial mins

    int tid = threadIdx.x;
    {
        const float* yb = targ + ((size_t)(b * N_ + mch * 256) + tid) * 3;
        float yx = yb[0], yy = yb[1], yz = yb[2];
        yt[tid] = make_float4(-2.f * yx, -2.f * yy, -2.f * yz,
                              yx * yx + yy * yy + yz * yz);
        if (tid < 4) yt[256 + tid] = make_float4(0.f, 0.f, 0.f, 0.f);  // prefetch pad
    }

    float rx[4], ry[4], rz[4], r2[4], rmin[4];
    const float* xb = pred + (size_t)(b * N_ + nch * 1024) * 3;
#pragma unroll
    for (int k = 0; k < 4; k++) {
        int r = k * 256 + tid;
        rx[k] = xb[3 * r]; ry[k] = xb[3 * r + 1]; rz[k] = xb[3 * r + 2];
        r2[k] = rx[k] * rx[k] + ry[k] * ry[k] + rz[k] * rz[k];
        rmin[k] = 3.4e38f;
    }
    __syncthreads();

    int lane = tid & 63, w = tid >> 6;
    float4 ya = yt[0], yb4 = yt[1];
#pragma unroll 2
    for (int m = 0; m < 256; m += 2) {
        float4 na = yt[m + 2], nb = yt[m + 3];   // prefetch next 2 cols
        float fa[4], fb[4];
#pragma unroll
        for (int k = 0; k < 4; k++) {
            // full d2 = |x|^2 + |y|^2 - 2 x.y  (seed carries both norms)
            fa[k] = fmaf(rx[k], ya.x,  fmaf(ry[k], ya.y,  fmaf(rz[k], ya.z,  ya.w  + r2[k])));
            fb[k] = fmaf(rx[k], yb4.x, fmaf(ry[k], yb4.y, fmaf(rz[k], yb4.z, yb4.w + r2[k])));
            rmin[k] = fminf(fminf(rmin[k], fa[k]), fb[k]);       // v_min3
        }
        // per-thread col partial (min over this thread's 4 rows)
        float ca = fminf(fminf(fminf(fa[0], fa[1]), fa[2]), fa[3]);
        float cb = fminf(fminf(fminf(fb[0], fb[1]), fb[2]), fb[3]);
        // 4-level butterfly -> min over each 16-lane group
#pragma unroll
        for (int off = 1; off <= 8; off <<= 1) {
            ca = fminf(ca, __shfl_xor(ca, off, 64));
            cb = fminf(cb, __shfl_xor(cb, off, 64));
        }
        if ((lane & 15) == 0) {
            clds[w][lane >> 4][m]     = ca;
            clds[w][lane >> 4][m + 1] = cb;
        }
        ya = na; yb4 = nb;
    }

    // row partials: full min-d2 over this block's 256 cols (seeded -> no shift)
    float* orow = pm + (size_t)mch * (B_ * N_) + b * N_ + nch * 1024;
#pragma unroll
    for (int k = 0; k < 4; k++) orow[k * 256 + tid] = rmin[k];

    __syncthreads();
    // col fold: 16 group-partials -> 1 per col, covering this block's 1024 rows
    {
        float v = clds[0][0][tid];
#pragma unroll
        for (int wv = 0; wv < 4; wv++)
#pragma unroll
            for (int g = 0; g < 4; g++)
                if (wv | g) v = fminf(v, clds[wv][g][tid]);
        float* ocol = pm + COL_OFF + (size_t)nch * (B_ * N_) + b * N_ + mch * 256;
        ocol[tid] = v;
    }
}

// 256 blocks x 256 threads over 65536 items:
//  idx <  32768: pred rows  -> min over 32 col-chunk slices
//  idx >= 32768: targ cols  -> min over 8 row-chunk slices
__global__ __launch_bounds__(256) void chamfer_reduce(const float* __restrict__ pm,
                                                      float* __restrict__ ws) {
    int idx = blockIdx.x * 256 + threadIdx.x;
    float v = 3.4e38f;
    if (idx < B_ * N_) {
#pragma unroll
        for (int s = 0; s < NROWSL; s++)
            v = fminf(v, pm[(size_t)s * (B_ * N_) + idx]);          // coalesced per s
    } else {
        int c = idx - B_ * N_;
        const float* pc = pm + COL_OFF;
#pragma unroll
        for (int s = 0; s < NCOLSL; s++)
            v = fminf(v, pc[(size_t)s * (B_ * N_) + c]);            // coalesced per s
    }
    float d = sqrtf(fmaxf(v, 0.f));                                  // maximum(d2,0)
    for (int off = 32; off; off >>= 1) d += __shfl_down(d, off, 64);
    __shared__ float red[4];
    int lane = threadIdx.x & 63, w = threadIdx.x >> 6;
    if (lane == 0) red[w] = d;
    __syncthreads();
    if (threadIdx.x == 0)
        ws[384 + blockIdx.x] = red[0] + red[1] + red[2] + red[3];
}

// 1 block x 256 threads: fold aux partials (128x3) + reduce partials (256).
__global__ __launch_bounds__(256) void compose(const float* __restrict__ ws,
                                               unsigned int* __restrict__ out) {
    int t = threadIdx.x;
    float dv = 0.f, sm = 0.f, sy = 0.f;
    if (t < 128) { dv = ws[3 * t]; sm = ws[3 * t + 1]; sy = ws[3 * t + 2]; }
    float rp = ws[384 + t];
    float cr = (t < 128) ? rp : 0.f;   // pred-side (row) sum blocks 0..127
    float cc = (t < 128) ? 0.f : rp;   // targ-side (col) sum blocks 128..255
    for (int off = 32; off; off >>= 1) {
        dv += __shfl_down(dv, off, 64);
        sm += __shfl_down(sm, off, 64);
        sy += __shfl_down(sy, off, 64);
        cr += __shfl_down(cr, off, 64);
        cc += __shfl_down(cc, off, 64);
    }
    __shared__ float red[5][4];
    int lane = t & 63, w = t >> 6;
    if (lane == 0) { red[0][w] = dv; red[1][w] = sm; red[2][w] = sy;
                     red[3][w] = cr; red[4][w] = cc; }
    __syncthreads();
    if (t == 0) {
        float S[5];
#pragma unroll
        for (int q = 0; q < 5; q++) S[q] = red[q][0] + red[q][1] + red[q][2] + red[q][3];
        float vertex = S[0] / (float)(B_ * N_ * 3);
        float smooth = S[1] / (float)(B_ * (N_ - 1));
        float sym    = S[2] / (float)(B_ * MID_ * 3);
        float cham   = (S[3] + S[4]) / (float)(B_ * N_);
        float total  = vertex + 0.1f * smooth + 0.05f * sym + 0.1f * cham;
        union { __hip_bfloat16 b; unsigned short u; } cv;
        cv.b = __float2bfloat16(total);
        // Dual-interpretation store (f32 read ~total, bf16-first-u16 read exact).
        out[0] = ((unsigned int)cv.u << 16) | (unsigned int)cv.u;
    }
}

extern "C" void kernel_launch(void* const* d_in, const int* in_sizes, int n_in,
                              void* d_out, int out_size, void* d_ws, size_t ws_size,
                              hipStream_t stream) {
    (void)in_sizes; (void)n_in; (void)out_size; (void)ws_size;
    const float* pred = (const float*)d_in[0];
    const float* targ = (const float*)d_in[1];
    float* wsf = (float*)d_ws;

    aux_losses<<<dim3(128), dim3(256), 0, stream>>>(pred, targ, wsf);
    chamfer_pairs<<<dim3(1024), dim3(256), 0, stream>>>(pred, targ, wsf + PMIN_OFF);
    chamfer_reduce<<<dim3(256), dim3(256), 0, stream>>>(wsf + PMIN_OFF, wsf);
    compose<<<dim3(1), dim3(256), 0, stream>>>(wsf, (unsigned int*)d_out);
}

// Round 2
// 101.634 us; speedup vs baseline: 1.2585x; 1.2585x over previous
//
#include <hip/hip_runtime.h>
#include <hip/hip_bf16.h>

// AdvancedLoss3D: vertex MSE + smoothness + symmetry + chamfer(B=4, N=8192)
// R17: revert to R15 two-pass structure (R16 fusion regressed: shfl-based
// col-reduction added dependent ds_swizzle chains, VALUBusy 103->66).
// R15 was ISSUE-bound (VALUBusy ~103%) -> only lever is fewer/wider VALU ops.
//  - Inner loop now packed FP32: v_pk_fma_f32 (2 fma/inst) + v_min3_f32.
//    Per 2 pair-visits: 3 pk_fma + 1 min3 = 4 issue slots (was 8).
//  - Row scalars broadcast into both packed halves via op_sel (rows kept as
//    packed (rx,ry) and (rz,r2) pairs -> no duplicated registers).
//  - LDS tile laid out as column-pair SoA: per 2 cols {(-2x0,-2x1),
//    (-2y0,-2y1),(-2z0,-2z1),(y2_0,y2_1)} -> 2 wave-uniform ds_read_b128.
//  - FP association identical to R15: ((y2 + rz*z) + ry*y) + rx*x, |x|^2
//    added in epilogue (min monotone under per-row shift).
//
// ws float layout (same as R15):
//  [0 .. 384)    aux partials: block b -> [3b]=vertex [3b+1]=smooth [3b+2]=sym
//  [384 .. 640)  reduce partials: block k -> sum of min-d for its 256 rows
//                (blocks 0..127 = pred-side rows, 128..255 = targ-side)
//  [1024 .. 1024+32*65536) per-slice chamfer partial mins pmins[mch][gid]

#define B_ 4
#define N_ 8192
#define MID_ (N_ / 2)
#define PMIN_OFF 1024

typedef float v2f __attribute__((ext_vector_type(2)));

// Template-named symbol (same mangling as the round-0 stub). Never launched.
__global__ void AdvancedLoss3D_1881195675843_kernel() {}

__global__ __launch_bounds__(256) void aux_losses(const float* __restrict__ pred,
                                                  const float* __restrict__ targ,
                                                  float* __restrict__ ws) {
    int idx = blockIdx.x * 256 + threadIdx.x;  // 0 .. B_*N_-1 (grid = 128 blocks)
    int b = idx >> 13;
    int i = idx & (N_ - 1);
    const float* p = pred + (size_t)idx * 3;
    const float* t = targ + (size_t)idx * 3;
    float px = p[0], py = p[1], pz = p[2];
    float tx = t[0], ty = t[1], tz = t[2];
    float dx = px - tx, dy = py - ty, dz = pz - tz;
    float dv = dx * dx + dy * dy + dz * dz;     // vertex MSE numerator

    float sm = 0.f;                             // smoothness: ||p[i+1]-p[i]||
    if (i < N_ - 1) {
        float ex = p[3] - px, ey = p[4] - py, ez = p[5] - pz;
        sm = sqrtf(ex * ex + ey * ey + ez * ez);
    }

    float sy = 0.f;                             // symmetry: partner N-1-i, x negated
    if (i < MID_) {
        const float* r = pred + ((size_t)(b * N_ + (N_ - 1 - i))) * 3;
        float ax = px + r[0];                   // left.x - (-right.x)
        float ay = py - r[1];
        float az = pz - r[2];
        sy = ax * ax + ay * ay + az * az;
    }

    for (int off = 32; off; off >>= 1) {
        dv += __shfl_down(dv, off, 64);
        sm += __shfl_down(sm, off, 64);
        sy += __shfl_down(sy, off, 64);
    }
    __shared__ float red[3][4];
    int lane = threadIdx.x & 63, w = threadIdx.x >> 6;
    if (lane == 0) { red[0][w] = dv; red[1][w] = sm; red[2][w] = sy; }
    __syncthreads();
    if (threadIdx.x == 0) {
        ws[3 * blockIdx.x + 0] = red[0][0] + red[0][1] + red[0][2] + red[0][3];
        ws[3 * blockIdx.x + 1] = red[1][0] + red[1][1] + red[1][2] + red[1][3];
        ws[3 * blockIdx.x + 2] = red[2][0] + red[2][1] + red[2][2] + red[2][3];
    }
}

// 1024 blocks: bid = dir(1) | b(2) | nch(2) | mch(5)
// block tile: 2048 rows (8/thread) x 256 cols (LDS, prescaled, pair-SoA)
__global__ __launch_bounds__(256) void chamfer_min(const float* __restrict__ pred,
                                                   const float* __restrict__ targ,
                                                   float* __restrict__ pmins) {
    int bid = blockIdx.x;
    int dir = bid >> 9;
    int b   = (bid >> 7) & 3;
    int nch = (bid >> 5) & 3;
    int mch = bid & 31;
    const float* X = dir ? targ : pred;
    const float* Y = dir ? pred : targ;

    // column-pair SoA: pair j -> 8 floats {xp0,xp1, yp0,yp1, zp0,zp1, w0,w1}
    __shared__ __align__(16) float yl[128 * 8];
    const float* ybase = Y + ((size_t)b * N_ + mch * 256) * 3;
    {
        int j = threadIdx.x;
        float yx = ybase[3 * j], yy = ybase[3 * j + 1], yz = ybase[3 * j + 2];
        int s = (j >> 1) * 8 + (j & 1);
        yl[s + 0] = -2.f * yx;
        yl[s + 2] = -2.f * yy;
        yl[s + 4] = -2.f * yz;
        yl[s + 6] = yx * yx + yy * yy + yz * yz;
    }

    v2f rxy[8], rzw[8];                // (rx,ry) and (rz,|x|^2)
    float rmin[8];
    const float* xbase = X + ((size_t)b * N_ + nch * 2048) * 3;
#pragma unroll
    for (int k = 0; k < 8; k++) {
        int r = k * 256 + threadIdx.x;
        float rx = xbase[3 * r], ry = xbase[3 * r + 1], rz = xbase[3 * r + 2];
        rxy[k] = (v2f){rx, ry};
        rzw[k] = (v2f){rz, rx * rx + ry * ry + rz * rz};
        rmin[k] = 3.4e38f;
    }
    __syncthreads();

    const float4* yl4 = (const float4*)yl;
#pragma unroll 2
    for (int m = 0; m < 128; m++) {
        float4 A  = yl4[2 * m];        // (xp0,xp1, yp0,yp1)  wave-uniform b128
        float4 Bq = yl4[2 * m + 1];    // (zp0,zp1, w0, w1)
        v2f xp  = (v2f){A.x, A.y};
        v2f ypr = (v2f){A.z, A.w};
        v2f zp  = (v2f){Bq.x, Bq.y};
        v2f wp  = (v2f){Bq.z, Bq.w};
#pragma unroll
        for (int k = 0; k < 8; k++) {
            v2f acc;
            // acc = rz*zp + w          (rz = rzw.lo broadcast via op_sel_hi)
            asm("v_pk_fma_f32 %0, %1, %2, %3 op_sel_hi:[0,1,1]"
                : "=v"(acc) : "v"(rzw[k]), "v"(zp), "v"(wp));
            // acc += ry*yp             (ry = rxy.hi broadcast via op_sel)
            asm("v_pk_fma_f32 %0, %1, %2, %0 op_sel:[1,0,0] op_sel_hi:[1,1,1]"
                : "+v"(acc) : "v"(rxy[k]), "v"(ypr));
            // acc += rx*xp             (rx = rxy.lo broadcast)
            asm("v_pk_fma_f32 %0, %1, %2, %0 op_sel_hi:[0,1,1]"
                : "+v"(acc) : "v"(rxy[k]), "v"(xp));
            // rmin = min(rmin, acc.lo, acc.hi)
            asm("v_min3_f32 %0, %0, %1, %2"
                : "+v"(rmin[k]) : "v"(acc.x), "v"(acc.y));
        }
    }

    float* out = pmins + (size_t)mch * (2 * B_ * N_) +
                 dir * (B_ * N_) + b * N_ + nch * 2048;
#pragma unroll
    for (int k = 0; k < 8; k++)
        out[k * 256 + threadIdx.x] = rmin[k] + rzw[k].y;   // = min d2 over slice
}

// 256 blocks x 256 threads over 65536 rows; min over 32 slices, clamp, sqrt, sum.
__global__ __launch_bounds__(256) void chamfer_reduce(const float* __restrict__ pmins,
                                                      float* __restrict__ ws) {
    int idx = blockIdx.x * 256 + threadIdx.x;
    float v = 3.4e38f;
#pragma unroll
    for (int s = 0; s < 32; s++)
        v = fminf(v, pmins[(size_t)s * (2 * B_ * N_) + idx]);   // coalesced per s
    float d = sqrtf(fmaxf(v, 0.f));                              // maximum(d2,0)
    for (int off = 32; off; off >>= 1) d += __shfl_down(d, off, 64);
    __shared__ float red[4];
    int lane = threadIdx.x & 63, w = threadIdx.x >> 6;
    if (lane == 0) red[w] = d;
    __syncthreads();
    if (threadIdx.x == 0)
        ws[384 + blockIdx.x] = red[0] + red[1] + red[2] + red[3];
}

// 1 block x 256 threads: fold aux partials (128x3) + reduce partials (256).
__global__ __launch_bounds__(256) void compose(const float* __restrict__ ws,
                                               unsigned int* __restrict__ out) {
    int t = threadIdx.x;
    float dv = 0.f, sm = 0.f, sy = 0.f;
    if (t < 128) { dv = ws[3 * t]; sm = ws[3 * t + 1]; sy = ws[3 * t + 2]; }
    float rp = ws[384 + t];
    float cr = (t < 128) ? rp : 0.f;   // pred-side (row) sum blocks 0..127
    float cc = (t < 128) ? 0.f : rp;   // targ-side (col) sum blocks 128..255
    for (int off = 32; off; off >>= 1) {
        dv += __shfl_down(dv, off, 64);
        sm += __shfl_down(sm, off, 64);
        sy += __shfl_down(sy, off, 64);
        cr += __shfl_down(cr, off, 64);
        cc += __shfl_down(cc, off, 64);
    }
    __shared__ float red[5][4];
    int lane = t & 63, w = t >> 6;
    if (lane == 0) { red[0][w] = dv; red[1][w] = sm; red[2][w] = sy;
                     red[3][w] = cr; red[4][w] = cc; }
    __syncthreads();
    if (t == 0) {
        float S[5];
#pragma unroll
        for (int q = 0; q < 5; q++) S[q] = red[q][0] + red[q][1] + red[q][2] + red[q][3];
        float vertex = S[0] / (float)(B_ * N_ * 3);
        float smooth = S[1] / (float)(B_ * (N_ - 1));
        float sym    = S[2] / (float)(B_ * MID_ * 3);
        float cham   = (S[3] + S[4]) / (float)(B_ * N_);
        float total  = vertex + 0.1f * smooth + 0.05f * sym + 0.1f * cham;
        union { __hip_bfloat16 b; unsigned short u; } cv;
        cv.b = __float2bfloat16(total);
        // Dual-interpretation store (f32 read ~total, bf16-first-u16 read exact).
        out[0] = ((unsigned int)cv.u << 16) | (unsigned int)cv.u;
    }
}

extern "C" void kernel_launch(void* const* d_in, const int* in_sizes, int n_in,
                              void* d_out, int out_size, void* d_ws, size_t ws_size,
                              hipStream_t stream) {
    (void)in_sizes; (void)n_in; (void)out_size; (void)ws_size;
    const float* pred = (const float*)d_in[0];
    const float* targ = (const float*)d_in[1];
    float* wsf = (float*)d_ws;

    aux_losses<<<dim3(128), dim3(256), 0, stream>>>(pred, targ, wsf);
    chamfer_min<<<dim3(1024), dim3(256), 0, stream>>>(pred, targ, wsf + PMIN_OFF);
    chamfer_reduce<<<dim3(256), dim3(256), 0, stream>>>(wsf + PMIN_OFF, wsf);
    compose<<<dim3(1), dim3(256), 0, stream>>>(wsf, (unsigned int*)d_out);
}